// Round 5
// baseline (778.346 us; speedup 1.0000x reference)
//
#include <hip/hip_runtime.h>
#include <hip/hip_bf16.h>
#include <math.h>
#include <type_traits>

// MoE: E=16, D=H=768, T=6304 tokens; fp32 in/out, bf16 internally for MFMA.
#define T_TOK 6304
#define DMODEL 768
#define NEXP 16
#define MOE_GRID 1024   // 4 blocks/CU x 256 CUs: co-resident (LDS 37.4KB -> 4/CU cap)

typedef __bf16 bf16x8 __attribute__((ext_vector_type(8)));
typedef float f32x4 __attribute__((ext_vector_type(4)));

__device__ __forceinline__ unsigned short f2bf(float f) {
    __hip_bfloat16 b = __float2bfloat16(f);   // RNE
    return __builtin_bit_cast(unsigned short, b);
}
__device__ __forceinline__ unsigned int pack2(float lo, float hi) {
    return (unsigned int)f2bf(lo) | ((unsigned int)f2bf(hi) << 16);
}

// ---------- prep: blocks [0,394) = gate (+x->bf16); [394,9610) = W1|W2 -> bf16 -------
__global__ __launch_bounds__(256) void prep_kernel(
    const float* __restrict__ x, const float* __restrict__ Wg,
    const float* __restrict__ bg, const float* __restrict__ W1,
    const float* __restrict__ W2, int* __restrict__ cnt, int* __restrict__ list,
    unsigned short* __restrict__ xb, unsigned short* __restrict__ w1b,
    unsigned short* __restrict__ w2b)
{
    if (blockIdx.x >= 394) {                 // weight convert: 8 floats/thread
        const int n8 = 1179648;              // 768*768*16 / 8
        int i = (blockIdx.x - 394) * 256 + threadIdx.x;   // [0, 2*n8)
        const float4* s; uint4* d; int j;
        if (i < n8) { s = (const float4*)W1; d = (uint4*)w1b; j = i; }
        else        { s = (const float4*)W2; d = (uint4*)w2b; j = i - n8; }
        float4 a = s[2 * j], b = s[2 * j + 1];
        d[j] = make_uint4(pack2(a.x, a.y), pack2(a.z, a.w),
                          pack2(b.x, b.y), pack2(b.z, b.w));
        return;
    }
    // gate: thread=(token,expert), fp64 dot, strict-> first-max argmax
    __shared__ double lg[16][17];
    const int tt = threadIdx.x >> 4;
    const int e  = threadIdx.x & 15;
    const int t  = blockIdx.x * 16 + tt;     // 6304 = 394*16
    const float4* xr = (const float4*)(x + (size_t)t * DMODEL);
    const float4* wr = (const float4*)(Wg + (size_t)e * DMODEL);
    double s0 = 0, s1 = 0, s2 = 0, s3 = 0;
#pragma unroll 4
    for (int i = 0; i < DMODEL / 4; ++i) {
        float4 a = xr[i], w = wr[i];
        s0 += (double)a.x * (double)w.x;
        s1 += (double)a.y * (double)w.y;
        s2 += (double)a.z * (double)w.z;
        s3 += (double)a.w * (double)w.w;
    }
    lg[tt][e] = (s0 + s1) + (s2 + s3);
    if (xb) {   // emit x row slice [e*48, e*48+48) as bf16
        uint4* dst = (uint4*)(xb + (size_t)t * DMODEL + e * 48);
#pragma unroll
        for (int u = 0; u < 6; ++u) {
            float4 a = xr[e * 12 + 2 * u], b = xr[e * 12 + 2 * u + 1];
            dst[u] = make_uint4(pack2(a.x, a.y), pack2(a.z, a.w),
                                pack2(b.x, b.y), pack2(b.z, b.w));
        }
    }
    __syncthreads();
    if (e == 0) {
        double best = -1e300; int bi = 0;
#pragma unroll
        for (int k = 0; k < NEXP; ++k) {
            double v = lg[tt][k] + (double)bg[k];
            if (v > best) { best = v; bi = k; }
        }
        int pos = atomicAdd(&cnt[bi], 1);
        list[bi * T_TOK + pos] = t;
    }
}

// ---------- one layer over all (e, nb, ys) tile units; persistent grid --------------
// BM=64 x BN=64 x BK=64, dbuf LDS, 1 barrier/K-iter. MFMA 16x16x32 bf16:
// A m=lane&15,k=(lane>>4)*8+j ; C/D col=lane&15,row=(lane>>4)*4+reg.
template<int GELU, typename TA, typename TW, typename TOUT>
__device__ __forceinline__ void run_tiles(
    const TA* __restrict__ in, const TW* __restrict__ W,
    const float* __restrict__ bias, const int* __restrict__ cnt,
    const int* __restrict__ list, TOUT* __restrict__ outp,
    unsigned short At[2][64][72], unsigned short Bt[2][64][72], int* toks)
{
    constexpr int BK = 64;
    constexpr bool A_F32 = std::is_same<TA, float>::value;
    constexpr bool W_F32 = std::is_same<TW, float>::value;
    const int tid = threadIdx.x, lane = tid & 63, w = tid >> 6;
    const int rg = w & 1, cg = w >> 1;
    const int l15 = lane & 15, q8 = (lane >> 4) * 8, q = lane >> 4;
    const int sr = tid >> 2, sk = (tid & 3) * 16;

    for (int v = blockIdx.x; v < NEXP * 96; v += MOE_GRID) {  // 1536 units
        const int e = v / 96, rr = v % 96, nb = rr >> 3, ys = rr & 7;
        const int c = cnt[e];
        const int n0 = nb * 64;
        const int* lst = list + e * T_TOK;
        const TW* bsrc = W + (size_t)e * DMODEL * DMODEL + (size_t)(n0 + sr) * DMODEL + sk;

        for (int yt = ys; yt * 64 < c; yt += 8) {
            const int m0 = yt * 64;
            __syncthreads();                 // prior tile's LDS use done
            if (tid < 64) {
                int mi = m0 + tid;
                toks[tid] = lst[mi < c ? mi : c - 1];
            }
            int ma = m0 + sr;
            const TA* asrc = in + (size_t)lst[ma < c ? ma : c - 1] * DMODEL + sk;

            f32x4 acc[2][2];
#pragma unroll
            for (int i = 0; i < 2; ++i)
#pragma unroll
                for (int j = 0; j < 2; ++j) acc[i][j] = (f32x4){0.f, 0.f, 0.f, 0.f};

            uint4 pa[2], pb[2];
            float4 fa[4], fb[4];
            auto load_regs = [&](int k0) {
                if constexpr (A_F32) {
                    const float4* s = (const float4*)(asrc + k0);
                    fa[0] = s[0]; fa[1] = s[1]; fa[2] = s[2]; fa[3] = s[3];
                } else {
                    const uint4* s = (const uint4*)(asrc + k0);
                    pa[0] = s[0]; pa[1] = s[1];
                }
                if constexpr (W_F32) {
                    const float4* s = (const float4*)(bsrc + k0);
                    fb[0] = s[0]; fb[1] = s[1]; fb[2] = s[2]; fb[3] = s[3];
                } else {
                    const uint4* s = (const uint4*)(bsrc + k0);
                    pb[0] = s[0]; pb[1] = s[1];
                }
            };
            auto store_tiles = [&](int buf) {
                if constexpr (A_F32) {
                    uint4 w0, w1;
                    w0.x = pack2(fa[0].x, fa[0].y); w0.y = pack2(fa[0].z, fa[0].w);
                    w0.z = pack2(fa[1].x, fa[1].y); w0.w = pack2(fa[1].z, fa[1].w);
                    w1.x = pack2(fa[2].x, fa[2].y); w1.y = pack2(fa[2].z, fa[2].w);
                    w1.z = pack2(fa[3].x, fa[3].y); w1.w = pack2(fa[3].z, fa[3].w);
                    *(uint4*)&At[buf][sr][sk] = w0; *(uint4*)&At[buf][sr][sk + 8] = w1;
                } else {
                    *(uint4*)&At[buf][sr][sk] = pa[0]; *(uint4*)&At[buf][sr][sk + 8] = pa[1];
                }
                if constexpr (W_F32) {
                    uint4 w0, w1;
                    w0.x = pack2(fb[0].x, fb[0].y); w0.y = pack2(fb[0].z, fb[0].w);
                    w0.z = pack2(fb[1].x, fb[1].y); w0.w = pack2(fb[1].z, fb[1].w);
                    w1.x = pack2(fb[2].x, fb[2].y); w1.y = pack2(fb[2].z, fb[2].w);
                    w1.z = pack2(fb[3].x, fb[3].y); w1.w = pack2(fb[3].z, fb[3].w);
                    *(uint4*)&Bt[buf][sr][sk] = w0; *(uint4*)&Bt[buf][sr][sk + 8] = w1;
                } else {
                    *(uint4*)&Bt[buf][sr][sk] = pb[0]; *(uint4*)&Bt[buf][sr][sk + 8] = pb[1];
                }
            };

            load_regs(0);
            store_tiles(0);
#pragma unroll 1
            for (int it = 0; it < DMODEL / BK; ++it) {
                __syncthreads();
                if (it + 1 < DMODEL / BK) load_regs((it + 1) * BK);
                const int buf = it & 1;
#pragma unroll
                for (int kk = 0; kk < BK; kk += 32) {
                    bf16x8 a0 = *(const bf16x8*)&At[buf][rg * 32 + l15][kk + q8];
                    bf16x8 a1 = *(const bf16x8*)&At[buf][rg * 32 + 16 + l15][kk + q8];
                    bf16x8 b0 = *(const bf16x8*)&Bt[buf][cg * 32 + l15][kk + q8];
                    bf16x8 b1 = *(const bf16x8*)&Bt[buf][cg * 32 + 16 + l15][kk + q8];
                    acc[0][0] = __builtin_amdgcn_mfma_f32_16x16x32_bf16(a0, b0, acc[0][0], 0, 0, 0);
                    acc[0][1] = __builtin_amdgcn_mfma_f32_16x16x32_bf16(a0, b1, acc[0][1], 0, 0, 0);
                    acc[1][0] = __builtin_amdgcn_mfma_f32_16x16x32_bf16(a1, b0, acc[1][0], 0, 0, 0);
                    acc[1][1] = __builtin_amdgcn_mfma_f32_16x16x32_bf16(a1, b1, acc[1][1], 0, 0, 0);
                }
                if (it + 1 < DMODEL / BK) store_tiles(buf ^ 1);
            }

#pragma unroll
            for (int i = 0; i < 2; ++i) {
#pragma unroll
                for (int j = 0; j < 2; ++j) {
                    int col = n0 + cg * 32 + j * 16 + l15;
                    float bv = bias[e * DMODEL + col];
#pragma unroll
                    for (int r = 0; r < 4; ++r) {
                        int mrow = rg * 32 + i * 16 + q * 4 + r;
                        if (m0 + mrow < c) {
                            float val = acc[i][j][r] + bv;
                            if (GELU) val = 0.5f * val * (1.f + erff(val * 0.70710678118654752f));
                            size_t idx = (size_t)toks[mrow] * DMODEL + col;
                            if constexpr (std::is_same<TOUT, float>::value) outp[idx] = val;
                            else outp[idx] = f2bf(val);
                        }
                    }
                }
            }
        }
    }
}

// Persistent fused MLP: layer1 -> device grid barrier -> layer2, one dispatch.
template<typename TA1, typename TW>
__global__ __launch_bounds__(256, 4) void moe_kernel(
    const TA1* __restrict__ in1, const TW* __restrict__ W1p, const float* __restrict__ b1,
    const TW* __restrict__ W2p, const float* __restrict__ b2,
    const int* __restrict__ cnt, const int* __restrict__ list,
    unsigned short* __restrict__ h, float* __restrict__ out, int* __restrict__ bar)
{
    __shared__ __align__(16) unsigned short At[2][64][72];
    __shared__ __align__(16) unsigned short Bt[2][64][72];
    __shared__ int toks[64];

    run_tiles<1, TA1, TW, unsigned short>(in1, W1p, b1, cnt, list, h, At, Bt, toks);

    // grid barrier: all h stores device-visible, then arrive+spin (agent scope)
    __threadfence();                         // drain + release this thread's stores
    __syncthreads();
    if (threadIdx.x == 0) {
        __hip_atomic_fetch_add(bar, 1, __ATOMIC_ACQ_REL, __HIP_MEMORY_SCOPE_AGENT);
        while (__hip_atomic_load(bar, __ATOMIC_ACQUIRE, __HIP_MEMORY_SCOPE_AGENT) < MOE_GRID) {}
    }
    __syncthreads();
    __threadfence();                         // acquire: invalidate stale caches

    run_tiles<0, unsigned short, TW, float>(h, W2p, b2, cnt, list, out, At, Bt, toks);
}

extern "C" void kernel_launch(void* const* d_in, const int* in_sizes, int n_in,
                              void* d_out, int out_size, void* d_ws, size_t ws_size,
                              hipStream_t stream)
{
    const float* x  = (const float*)d_in[0];
    const float* W1 = (const float*)d_in[1];
    const float* b1 = (const float*)d_in[2];
    const float* W2 = (const float*)d_in[3];
    const float* b2 = (const float*)d_in[4];
    const float* Wg = (const float*)d_in[5];
    const float* bg = (const float*)d_in[6];
    float* out = (float*)d_out;

    char* ws   = (char*)d_ws;
    int*  cnt  = (int*)ws;                                  // 64 B
    int*  bar  = (int*)(ws + 64);                           // 4 B (grid barrier)
    int*  list = (int*)(ws + 256);                          // 403,456 B
    unsigned short* xb  = (unsigned short*)(ws + 403712);   // 9,682,944 B
    unsigned short* h   = (unsigned short*)(ws + 10086656); // 9,682,944 B
    unsigned short* w1b = (unsigned short*)(ws + 19769600); // 18,874,368 B
    unsigned short* w2b = (unsigned short*)(ws + 38643968); // 18,874,368 B
    const bool big = ws_size >= (size_t)57518336;

    hipMemsetAsync(ws, 0, 256, stream);                     // cnt + bar
    if (big) {
        prep_kernel<<<dim3(394 + 9216), dim3(256), 0, stream>>>(
            x, Wg, bg, W1, W2, cnt, list, xb, w1b, w2b);
        moe_kernel<unsigned short, unsigned short><<<dim3(MOE_GRID), dim3(256), 0, stream>>>(
            xb, w1b, b1, w2b, b2, cnt, list, h, out, bar);
    } else {   // fallback: fp32 weights/x with fused bf16 staging
        prep_kernel<<<dim3(394), dim3(256), 0, stream>>>(
            x, Wg, bg, W1, W2, cnt, list, nullptr, nullptr, nullptr);
        moe_kernel<float, float><<<dim3(MOE_GRID), dim3(256), 0, stream>>>(
            x, W1, b1, W2, b2, cnt, list, h, out, bar);
    }
}

// Round 6
// 342.984 us; speedup vs baseline: 2.2693x; 2.2693x over previous
//
#include <hip/hip_runtime.h>
#include <hip/hip_bf16.h>
#include <math.h>
#include <type_traits>

// MoE: E=16, D=H=768, T=6304 tokens; fp32 in/out, bf16 internally for MFMA.
#define T_TOK 6304
#define DMODEL 768
#define NEXP 16

typedef __bf16 bf16x8 __attribute__((ext_vector_type(8)));
typedef float f32x4 __attribute__((ext_vector_type(4)));

__device__ __forceinline__ unsigned short f2bf(float f) {
    __hip_bfloat16 b = __float2bfloat16(f);   // RNE
    return __builtin_bit_cast(unsigned short, b);
}
__device__ __forceinline__ unsigned int pack2(float lo, float hi) {
    return (unsigned int)f2bf(lo) | ((unsigned int)f2bf(hi) << 16);
}

// ---------- prep: blocks [0,394) = gate (+x->bf16); [394,9610) = W1|W2 -> bf16 -------
__global__ __launch_bounds__(256) void prep_kernel(
    const float* __restrict__ x, const float* __restrict__ Wg,
    const float* __restrict__ bg, const float* __restrict__ W1,
    const float* __restrict__ W2, int* __restrict__ cnt, int* __restrict__ list,
    unsigned short* __restrict__ xb, unsigned short* __restrict__ w1b,
    unsigned short* __restrict__ w2b)
{
    if (blockIdx.x >= 394) {                 // weight convert: 8 floats/thread
        const int n8 = 1179648;              // 768*768*16 / 8
        int i = (blockIdx.x - 394) * 256 + threadIdx.x;   // [0, 2*n8)
        const float4* s; uint4* d; int j;
        if (i < n8) { s = (const float4*)W1; d = (uint4*)w1b; j = i; }
        else        { s = (const float4*)W2; d = (uint4*)w2b; j = i - n8; }
        float4 a = s[2 * j], b = s[2 * j + 1];
        d[j] = make_uint4(pack2(a.x, a.y), pack2(a.z, a.w),
                          pack2(b.x, b.y), pack2(b.z, b.w));
        return;
    }
    // gate: thread=(token,expert), fp64 dot, strict-> first-max argmax (np semantics)
    __shared__ double lg[16][17];
    const int tt = threadIdx.x >> 4;
    const int e  = threadIdx.x & 15;
    const int t  = blockIdx.x * 16 + tt;     // 6304 = 394*16
    const float4* xr = (const float4*)(x + (size_t)t * DMODEL);
    const float4* wr = (const float4*)(Wg + (size_t)e * DMODEL);
    double s0 = 0, s1 = 0, s2 = 0, s3 = 0;
#pragma unroll 4
    for (int i = 0; i < DMODEL / 4; ++i) {
        float4 a = xr[i], w = wr[i];
        s0 += (double)a.x * (double)w.x;
        s1 += (double)a.y * (double)w.y;
        s2 += (double)a.z * (double)w.z;
        s3 += (double)a.w * (double)w.w;
    }
    lg[tt][e] = (s0 + s1) + (s2 + s3);
    if (xb) {   // emit x row slice [e*48, e*48+48) as bf16
        uint4* dst = (uint4*)(xb + (size_t)t * DMODEL + e * 48);
#pragma unroll
        for (int u = 0; u < 6; ++u) {
            float4 a = xr[e * 12 + 2 * u], b = xr[e * 12 + 2 * u + 1];
            dst[u] = make_uint4(pack2(a.x, a.y), pack2(a.z, a.w),
                                pack2(b.x, b.y), pack2(b.z, b.w));
        }
    }
    __syncthreads();
    if (e == 0) {
        double best = -1e300; int bi = 0;
#pragma unroll
        for (int k = 0; k < NEXP; ++k) {
            double v = lg[tt][k] + (double)bg[k];
            if (v > best) { best = v; bi = k; }
        }
        int pos = atomicAdd(&cnt[bi], 1);
        list[bi * T_TOK + pos] = t;
    }
}

// ---------- gathered expert GEMM, double-buffered LDS, 1 barrier per K-iter ----------
// BM=64 x BN=64 x BK=64; 4 waves, wave tile 32x32. Persistent y-stride (no dead blocks).
// MFMA 16x16x32 bf16: A m=lane&15,k=(lane>>4)*8+j ; C/D col=lane&15,row=(lane>>4)*4+reg.
template<int GELU, typename TA, typename TW, typename TOUT>
__global__ __launch_bounds__(256, 4) void expert_layer(
    const TA* __restrict__ in, const TW* __restrict__ W,
    const float* __restrict__ bias, const int* __restrict__ cnt,
    const int* __restrict__ list, TOUT* __restrict__ outp)
{
    constexpr int BK = 64, LDK = 72;   // pad: 144B row stride, 2-way bank alias (free)
    constexpr bool A_F32 = std::is_same<TA, float>::value;
    constexpr bool W_F32 = std::is_same<TW, float>::value;
    __shared__ __align__(16) unsigned short At[2][64][LDK];
    __shared__ __align__(16) unsigned short Bt[2][64][LDK];
    __shared__ int toks[64];

    const int bx = blockIdx.x;              // = e*12 + nb : consecutive bx spread XCDs
    const int e = bx / 12, nb = bx % 12;
    const int c = cnt[e];
    const int n0 = nb * 64;
    const int tid = threadIdx.x, lane = tid & 63, w = tid >> 6;
    const int rg = w & 1, cg = w >> 1;
    const int l15 = lane & 15, q8 = (lane >> 4) * 8, q = lane >> 4;
    const int sr = tid >> 2, sk = (tid & 3) * 16;

    const TW* bsrc = W + (size_t)e * DMODEL * DMODEL + (size_t)(n0 + sr) * DMODEL + sk;
    const int* lst = list + e * T_TOK;

    uint4 pa[2], pb[2];
    float4 fa[4], fb[4];

    for (int yt = blockIdx.y; yt * 64 < c; yt += 8) {
        const int m0 = yt * 64;
        __syncthreads();                     // prior y-iter epilogue done (toks reuse)
        if (tid < 64) {
            int mi = m0 + tid;
            toks[tid] = lst[mi < c ? mi : c - 1];
        }
        int ma = m0 + sr;
        const TA* asrc = in + (size_t)lst[ma < c ? ma : c - 1] * DMODEL + sk;

        f32x4 acc[2][2];
#pragma unroll
        for (int i = 0; i < 2; ++i)
#pragma unroll
            for (int j = 0; j < 2; ++j) acc[i][j] = (f32x4){0.f, 0.f, 0.f, 0.f};

        auto load_regs = [&](int k0) {
            if constexpr (A_F32) {
                const float4* s = (const float4*)(asrc + k0);
                fa[0] = s[0]; fa[1] = s[1]; fa[2] = s[2]; fa[3] = s[3];
            } else {
                const uint4* s = (const uint4*)(asrc + k0);
                pa[0] = s[0]; pa[1] = s[1];
            }
            if constexpr (W_F32) {
                const float4* s = (const float4*)(bsrc + k0);
                fb[0] = s[0]; fb[1] = s[1]; fb[2] = s[2]; fb[3] = s[3];
            } else {
                const uint4* s = (const uint4*)(bsrc + k0);
                pb[0] = s[0]; pb[1] = s[1];
            }
        };
        auto store_tiles = [&](int buf) {
            if constexpr (A_F32) {
                uint4 w0, w1;
                w0.x = pack2(fa[0].x, fa[0].y); w0.y = pack2(fa[0].z, fa[0].w);
                w0.z = pack2(fa[1].x, fa[1].y); w0.w = pack2(fa[1].z, fa[1].w);
                w1.x = pack2(fa[2].x, fa[2].y); w1.y = pack2(fa[2].z, fa[2].w);
                w1.z = pack2(fa[3].x, fa[3].y); w1.w = pack2(fa[3].z, fa[3].w);
                *(uint4*)&At[buf][sr][sk] = w0; *(uint4*)&At[buf][sr][sk + 8] = w1;
            } else {
                *(uint4*)&At[buf][sr][sk] = pa[0]; *(uint4*)&At[buf][sr][sk + 8] = pa[1];
            }
            if constexpr (W_F32) {
                uint4 w0, w1;
                w0.x = pack2(fb[0].x, fb[0].y); w0.y = pack2(fb[0].z, fb[0].w);
                w0.z = pack2(fb[1].x, fb[1].y); w0.w = pack2(fb[1].z, fb[1].w);
                w1.x = pack2(fb[2].x, fb[2].y); w1.y = pack2(fb[2].z, fb[2].w);
                w1.z = pack2(fb[3].x, fb[3].y); w1.w = pack2(fb[3].z, fb[3].w);
                *(uint4*)&Bt[buf][sr][sk] = w0; *(uint4*)&Bt[buf][sr][sk + 8] = w1;
            } else {
                *(uint4*)&Bt[buf][sr][sk] = pb[0]; *(uint4*)&Bt[buf][sr][sk + 8] = pb[1];
            }
        };

        load_regs(0);
        store_tiles(0);
#pragma unroll 1
        for (int it = 0; it < DMODEL / BK; ++it) {
            __syncthreads();                 // buf[it&1] ready
            if (it + 1 < DMODEL / BK) load_regs((it + 1) * BK);
            const int buf = it & 1;
#pragma unroll
            for (int kk = 0; kk < BK; kk += 32) {
                bf16x8 a0 = *(const bf16x8*)&At[buf][rg * 32 + l15][kk + q8];
                bf16x8 a1 = *(const bf16x8*)&At[buf][rg * 32 + 16 + l15][kk + q8];
                bf16x8 b0 = *(const bf16x8*)&Bt[buf][cg * 32 + l15][kk + q8];
                bf16x8 b1 = *(const bf16x8*)&Bt[buf][cg * 32 + 16 + l15][kk + q8];
                acc[0][0] = __builtin_amdgcn_mfma_f32_16x16x32_bf16(a0, b0, acc[0][0], 0, 0, 0);
                acc[0][1] = __builtin_amdgcn_mfma_f32_16x16x32_bf16(a0, b1, acc[0][1], 0, 0, 0);
                acc[1][0] = __builtin_amdgcn_mfma_f32_16x16x32_bf16(a1, b0, acc[1][0], 0, 0, 0);
                acc[1][1] = __builtin_amdgcn_mfma_f32_16x16x32_bf16(a1, b1, acc[1][1], 0, 0, 0);
            }
            if (it + 1 < DMODEL / BK) store_tiles(buf ^ 1);  // peers read buf only
        }

        // epilogue: bias (+ exact GELU), scatter rows by token
#pragma unroll
        for (int i = 0; i < 2; ++i) {
#pragma unroll
            for (int j = 0; j < 2; ++j) {
                int col = n0 + cg * 32 + j * 16 + l15;
                float bv = bias[e * DMODEL + col];
#pragma unroll
                for (int r = 0; r < 4; ++r) {
                    int mrow = rg * 32 + i * 16 + q * 4 + r;
                    if (m0 + mrow < c) {
                        float val = acc[i][j][r] + bv;
                        if (GELU) val = 0.5f * val * (1.f + erff(val * 0.70710678118654752f));
                        size_t idx = (size_t)toks[mrow] * DMODEL + col;
                        if constexpr (std::is_same<TOUT, float>::value) outp[idx] = val;
                        else outp[idx] = f2bf(val);
                    }
                }
            }
        }
    }
}

extern "C" void kernel_launch(void* const* d_in, const int* in_sizes, int n_in,
                              void* d_out, int out_size, void* d_ws, size_t ws_size,
                              hipStream_t stream)
{
    const float* x  = (const float*)d_in[0];
    const float* W1 = (const float*)d_in[1];
    const float* b1 = (const float*)d_in[2];
    const float* W2 = (const float*)d_in[3];
    const float* b2 = (const float*)d_in[4];
    const float* Wg = (const float*)d_in[5];
    const float* bg = (const float*)d_in[6];
    float* out = (float*)d_out;

    char* ws   = (char*)d_ws;
    int*  cnt  = (int*)ws;                                  // 64 B
    int*  list = (int*)(ws + 256);                          // 403,456 B
    unsigned short* xb  = (unsigned short*)(ws + 403712);   // 9,682,944 B
    unsigned short* h   = (unsigned short*)(ws + 10086656); // 9,682,944 B
    unsigned short* w1b = (unsigned short*)(ws + 19769600); // 18,874,368 B
    unsigned short* w2b = (unsigned short*)(ws + 38643968); // 18,874,368 B
    const bool big = ws_size >= (size_t)57518336;

    hipMemsetAsync(cnt, 0, 256, stream);
    dim3 grid(12 * NEXP, 8);   // 192 x 8; persistent y-stride, no dead blocks
    if (big) {
        prep_kernel<<<dim3(394 + 9216), dim3(256), 0, stream>>>(
            x, Wg, bg, W1, W2, cnt, list, xb, w1b, w2b);
        expert_layer<1, unsigned short, unsigned short, unsigned short>
            <<<grid, dim3(256), 0, stream>>>(xb, w1b, b1, cnt, list, h);
        expert_layer<0, unsigned short, unsigned short, float>
            <<<grid, dim3(256), 0, stream>>>(h, w2b, b2, cnt, list, out);
    } else {   // fallback: fp32 inputs with fused bf16 staging
        prep_kernel<<<dim3(394), dim3(256), 0, stream>>>(
            x, Wg, bg, W1, W2, cnt, list, nullptr, nullptr, nullptr);
        expert_layer<1, float, float, unsigned short>
            <<<grid, dim3(256), 0, stream>>>(x, W1, b1, cnt, list, h);
        expert_layer<0, unsigned short, float, float>
            <<<grid, dim3(256), 0, stream>>>(h, W2, b2, cnt, list, out);
    }
}